// Round 13
// baseline (405.020 us; speedup 1.0000x reference)
//
#include <hip/hip_runtime.h>
#include <hip/hip_bf16.h>
#include <hip/hip_cooperative_groups.h>

namespace cg = cooperative_groups;

#define N_NODES 50000
#define N_EDGES 800000
#define HID 128

#define NB 391      // dst buckets: dst>>7, 128 nodes each
#define NBLK 160    // build blocks
#define EPB 5000    // edges per block (NBLK*EPB == N_EDGES)

typedef __attribute__((ext_vector_type(8))) short short8;     // 8 bf16 (4 VGPR)
typedef __attribute__((ext_vector_type(4))) float f32x4;      // MFMA acc
typedef __attribute__((ext_vector_type(4))) unsigned short us4;
typedef _Float16 hv8 __attribute__((ext_vector_type(8)));     // 8 fp16 (16 B)
typedef _Float16 hv4 __attribute__((ext_vector_type(4)));     // 4 fp16 (8 B)

__device__ __forceinline__ unsigned short f2bf(float v) {
    union { float f; unsigned u; } x; x.f = v;
    unsigned r = x.u + 0x7fff + ((x.u >> 16) & 1);   // RTN-even
    return (unsigned short)(r >> 16);
}
__device__ __forceinline__ float bf2f(unsigned short b) {
    union { unsigned u; float f; } x; x.u = ((unsigned)b) << 16;
    return x.f;
}

// --------------------- single cooperative kernel: CSR build + converts
// 160 blocks x 256. Phases (grid.sync between):
//  H: per-block LDS histogram of dst buckets -> bh[bucket*NBLK + blk]
//  X: (independent) x -> fp16 table; W -> fragment-major bf16 hi/lo
//  S1: chunk sums of flat bh (391 ints/block) -> gsum
//  S2: block 0 exclusive-scans gsum[160]
//  S3: per-chunk local scan + chunk offset -> bhs (flat exclusive scan)
//  C: scatter edges into bucket-segmented tmp (packed src<<7|dst&127)
//  D: per-bucket 128-counter sort -> offs + csr (blocks stride over 391)
// W fragment-major layout (verified R12): 128-col mats, element (k,n) ->
// ((w*8+ks*2+ct)*64 + quad*16+m)*8 + j  with n=w*32+ct*16+m, k=ks*32+quad*8+j;
// W_h1: ((w*4+ks)*64 + quad*16+m)*8 + j, n=w*16+m.
__global__ __launch_bounds__(256)
void build_k(const int* __restrict__ src, const int* __restrict__ dst,
             int* __restrict__ bh, int* __restrict__ gsum, int* __restrict__ bhs,
             int* __restrict__ tmp, int* __restrict__ offs, int* __restrict__ csr,
             const float* __restrict__ x, _Float16* __restrict__ xh,
             const float* __restrict__ Wa, const float* __restrict__ Wb,
             const float* __restrict__ Wh1,
             unsigned short* __restrict__ whi, unsigned short* __restrict__ wlo) {
    cg::grid_group grid = cg::this_grid();
    const int blk = blockIdx.x, t = threadIdx.x;
    __shared__ int sh[NB];
    __shared__ int red[256];
    __shared__ int hist[128], excl[128], cur[128];

    // ---- phase H: histogram
    for (int i = t; i < NB; i += 256) sh[i] = 0;
    __syncthreads();
    {
        const int base = blk * EPB;
        for (int i = base + t; i < base + EPB; i += 256)
            atomicAdd(&sh[dst[i] >> 7], 1);
    }
    __syncthreads();
    for (int i = t; i < NB; i += 256) bh[i * NBLK + blk] = sh[i];

    // ---- phase X: converts (no dependency on H)
    {
        const int base = blk * 10000;                 // 160*10000 = 1.6M exact
        for (int q = t; q < 10000; q += 256) {
            int i = base + q;
            float4 v = *(const float4*)&x[i * 4];
            hv4 o;
            o.x = (_Float16)v.x; o.y = (_Float16)v.y;
            o.z = (_Float16)v.z; o.w = (_Float16)v.w;
            *(hv4*)&xh[i * 4] = o;
        }
        for (int q = t; q < 666; q += 256) {          // 160*666 >= 106,496
            int id = blk * 666 + q;
            float v; int dsti;
            if (id < 98304) {
                int isB = (id >= 49152);
                int id2 = isB ? id - 49152 : id;
                int l = id2 >> 14, e = id2 & 16383;
                v = isB ? Wb[id2] : Wa[id2];
                int k = e >> 7, n = e & 127;
                int w = n >> 5, ct = (n >> 4) & 1, m = n & 15;
                int ks = k >> 5, quad = (k >> 3) & 3, j = k & 7;
                dsti = (2 * l + isB) * 16384 +
                       ((w * 8 + ks * 2 + ct) * 64 + quad * 16 + m) * 8 + j;
            } else if (id < 106496) {
                int e = id - 98304;
                v = Wh1[e];
                int k = e >> 6, n = e & 63;
                int w = n >> 4, m = n & 15;
                int ks = k >> 5, quad = (k >> 3) & 3, j = k & 7;
                dsti = 6 * 16384 + ((w * 4 + ks) * 64 + quad * 16 + m) * 8 + j;
            } else continue;
            unsigned short hi = f2bf(v);
            whi[dsti] = hi;
            wlo[dsti] = f2bf(v - bf2f(hi));
        }
    }
    grid.sync();

    // ---- phase S1: chunk sums (M = 62,560 = 160 x 391 flat)
    {
        const int base = blk * 391;
        int s = 0;
        for (int i = t; i < 391; i += 256) s += bh[base + i];
        red[t] = s;
        __syncthreads();
        for (int o = 128; o > 0; o >>= 1) {
            if (t < o) red[t] += red[t + o];
            __syncthreads();
        }
        if (t == 0) gsum[blk] = red[0];
    }
    grid.sync();

    // ---- phase S2: block 0 exclusive scan of gsum[160]
    if (blk == 0) {
        int v = (t < NBLK) ? gsum[t] : 0;
        red[t] = v;
        __syncthreads();
        for (int o = 1; o < 256; o <<= 1) {
            int u = (t >= o) ? red[t - o] : 0;
            __syncthreads();
            red[t] += u;
            __syncthreads();
        }
        if (t < NBLK) gsum[t] = red[t] - v;
    }
    grid.sync();

    // ---- phase S3: local scan of chunk + base -> bhs
    {
        const int base = blk * 391;
        int i0 = t * 2, i1 = t * 2 + 1;
        int v0 = (i0 < 391) ? bh[base + i0] : 0;
        int v1 = (i1 < 391) ? bh[base + i1] : 0;
        red[t] = v0 + v1;
        __syncthreads();
        for (int o = 1; o < 256; o <<= 1) {
            int u = (t >= o) ? red[t - o] : 0;
            __syncthreads();
            red[t] += u;
            __syncthreads();
        }
        int ex = ((t == 0) ? 0 : red[t - 1]) + gsum[blk];
        if (i0 < 391) bhs[base + i0] = ex;
        if (i1 < 391) bhs[base + i1] = ex + v0;
    }
    grid.sync();

    // ---- phase C: scatter
    for (int i = t; i < NB; i += 256) sh[i] = bhs[i * NBLK + blk];
    __syncthreads();
    {
        const int base = blk * EPB;
        for (int i = base + t; i < base + EPB; i += 256) {
            int d = dst[i];
            int p = atomicAdd(&sh[d >> 7], 1);
            tmp[p] = (src[i] << 7) | (d & 127);
        }
    }
    grid.sync();

    // ---- phase D: per-bucket local sort -> offs + csr
    if (blk == 0 && t == 0) offs[N_NODES] = N_EDGES;
    for (int b = blk; b < NB; b += NBLK) {
        const int bstart = bhs[b * NBLK];
        const int bend = (b + 1 < NB) ? bhs[(b + 1) * NBLK] : N_EDGES;
        if (t < 128) hist[t] = 0;
        __syncthreads();
        for (int i = bstart + t; i < bend; i += 256)
            atomicAdd(&hist[tmp[i] & 127], 1);
        __syncthreads();
        if (t < 128) excl[t] = hist[t];
        __syncthreads();
        for (int o = 1; o < 128; o <<= 1) {
            int u = (t < 128 && t >= o) ? excl[t - o] : 0;
            __syncthreads();
            if (t < 128) excl[t] += u;
            __syncthreads();
        }
        const int node0 = b * 128;
        if (t < 128) {
            int base = bstart + ((t == 0) ? 0 : excl[t - 1]);
            if (node0 + t < N_NODES) offs[node0 + t] = base;
            cur[t] = base;
        }
        __syncthreads();
        for (int i = bstart + t; i < bend; i += 256) {
            int e = tmp[i];
            int p = atomicAdd(&cur[e & 127], 1);
            csr[p] = e >> 7;
        }
        __syncthreads();
    }
}

// ------------------------------------------- standalone gather-aggregate
// Pure gather kernel: 16 nodes per 256-block, one quarter-wave
// (16 lanes x hv8 = full 256 B row) per node, unroll-4.
__global__ __launch_bounds__(256)
void agg16_k(const _Float16* __restrict__ h_in,
             const int* __restrict__ offs, const int* __restrict__ csr,
             const float* __restrict__ eps, int layer,
             _Float16* __restrict__ z) {
    const int qw = threadIdx.x >> 4;           // 0..15
    const int l16 = threadIdx.x & 15;
    const int node = blockIdx.x * 16 + qw;
    if (node >= N_NODES) return;
    const hv8* __restrict__ h8 = (const hv8*)h_in;   // row = 16 hv8
    const float sc = 1.0f + eps[layer];
    const int beg = offs[node], end = offs[node + 1];
    float a0[8] = {0,0,0,0,0,0,0,0};
    float a1[8] = {0,0,0,0,0,0,0,0};
    int j = beg;
    for (; j + 4 <= end; j += 4) {
        int s0 = csr[j], s1 = csr[j+1], s2 = csr[j+2], s3 = csr[j+3];
        hv8 v0 = h8[(size_t)s0 * 16 + l16];
        hv8 v1 = h8[(size_t)s1 * 16 + l16];
        hv8 v2 = h8[(size_t)s2 * 16 + l16];
        hv8 v3 = h8[(size_t)s3 * 16 + l16];
#pragma unroll
        for (int e = 0; e < 8; ++e) {
            a0[e] += (float)v0[e] + (float)v2[e];
            a1[e] += (float)v1[e] + (float)v3[e];
        }
    }
    for (; j < end; ++j) {
        hv8 v = h8[(size_t)csr[j] * 16 + l16];
#pragma unroll
        for (int e = 0; e < 8; ++e) a0[e] += (float)v[e];
    }
    hv8 self = h8[(size_t)node * 16 + l16];
    hv8 o;
#pragma unroll
    for (int e = 0; e < 8; ++e)
        o[e] = (_Float16)(sc * (float)self[e] + (a0[e] + a1[e]));
    ((hv8*)z)[(size_t)node * 16 + l16] = o;
}

// ------------------------------------------------------- MLP kernel (v4)
// One block = 64 rows (grid 782). Fragment-major W, streamed per k-step.
// !HEAD h-store now goes through LDS restage -> coalesced hv8 global
// stores (R12's scalar 2B scattered stores caused write-allocate RMW).
// FP accumulate order per acc element unchanged (ks ascending).
template <bool HEAD>
__global__ __launch_bounds__(256)
void mlp_k(const _Float16* __restrict__ z_in,
           const unsigned short* __restrict__ WAhi, const unsigned short* __restrict__ WAlo,
           const float* __restrict__ ba,
           const unsigned short* __restrict__ WBhi, const unsigned short* __restrict__ WBlo,
           const float* __restrict__ bb,
           const unsigned short* __restrict__ WHhi, const unsigned short* __restrict__ WHlo,
           const float* __restrict__ bh1,
           const float* __restrict__ W2, const float* __restrict__ b2,
           void* __restrict__ outp) {
    __shared__ unsigned short Zhi[64 * 136];   // 17,408 B
    __shared__ unsigned short Zlo[64 * 136];
    const int t = threadIdx.x;
    const int wave = t >> 6, lane = t & 63;
    const int m = lane & 15, quad = lane >> 4;
    const int row0 = blockIdx.x * 64;

    // ---------- stage z -> LDS bf16 hi/lo (coalesced hv8 reads)
    {
        const int quart = lane >> 4, l16 = lane & 15;
        const hv8* __restrict__ z8 = (const hv8*)z_in;
        for (int g = 0; g < 4; ++g) {
            const int r = wave * 16 + g * 4 + quart;
            const int node = row0 + r;
            float o[8] = {0,0,0,0,0,0,0,0};
            if (node < N_NODES) {
                hv8 v = z8[(size_t)node * 16 + l16];
#pragma unroll
                for (int e = 0; e < 8; ++e) o[e] = (float)v[e];
            }
            us4 hi0, hi1, lo0, lo1;
#pragma unroll
            for (int e = 0; e < 4; ++e) {
                hi0[e] = f2bf(o[e]);     lo0[e] = f2bf(o[e]     - bf2f(hi0[e]));
                hi1[e] = f2bf(o[e + 4]); lo1[e] = f2bf(o[e + 4] - bf2f(hi1[e]));
            }
            *(us4*)&Zhi[r * 136 + l16 * 8]     = hi0;
            *(us4*)&Zhi[r * 136 + l16 * 8 + 4] = hi1;
            *(us4*)&Zlo[r * 136 + l16 * 8]     = lo0;
            *(us4*)&Zlo[r * 136 + l16 * 8 + 4] = lo1;
        }
    }
    __syncthreads();

    // ---------- phase 2: z @ W_a (fragment-major W, streamed per ks)
    f32x4 acc[4][2];
    for (int s = 0; s < 4; ++s)
        for (int ct = 0; ct < 2; ++ct) acc[s][ct] = (f32x4){0, 0, 0, 0};
#pragma unroll 1
    for (int ks = 0; ks < 4; ++ks) {
        const int fA = (wave * 8 + ks * 2) * 512 + lane * 8;
        short8 wh0 = *(const short8*)&WAhi[fA];
        short8 wl0 = *(const short8*)&WAlo[fA];
        short8 wh1 = *(const short8*)&WAhi[fA + 512];
        short8 wl1 = *(const short8*)&WAlo[fA + 512];
        const int wo = ks * 32 + quad * 8;
#pragma unroll
        for (int s = 0; s < 4; ++s) {
            const int r = s * 16 + m;
            short8 zh = *(const short8*)&Zhi[r * 136 + wo];
            short8 zl = *(const short8*)&Zlo[r * 136 + wo];
            acc[s][0] = __builtin_amdgcn_mfma_f32_16x16x32_bf16(zh, wh0, acc[s][0], 0, 0, 0);
            acc[s][0] = __builtin_amdgcn_mfma_f32_16x16x32_bf16(zh, wl0, acc[s][0], 0, 0, 0);
            acc[s][0] = __builtin_amdgcn_mfma_f32_16x16x32_bf16(zl, wh0, acc[s][0], 0, 0, 0);
            acc[s][1] = __builtin_amdgcn_mfma_f32_16x16x32_bf16(zh, wh1, acc[s][1], 0, 0, 0);
            acc[s][1] = __builtin_amdgcn_mfma_f32_16x16x32_bf16(zh, wl1, acc[s][1], 0, 0, 0);
            acc[s][1] = __builtin_amdgcn_mfma_f32_16x16x32_bf16(zl, wh1, acc[s][1], 0, 0, 0);
        }
    }
    __syncthreads();   // all z reads done; safe to overwrite LDS

    // ---------- u = relu(acc + ba) -> LDS bf16 hi/lo
    for (int s = 0; s < 4; ++s) {
        for (int ct = 0; ct < 2; ++ct) {
            int c = wave * 32 + ct * 16 + m;
            float bac = ba[c];
            for (int i = 0; i < 4; ++i) {
                int r = s * 16 + quad * 4 + i;
                float v = fmaxf(acc[s][ct][i] + bac, 0.0f);
                unsigned short hv = f2bf(v);
                Zhi[r * 136 + c] = hv;
                Zlo[r * 136 + c] = f2bf(v - bf2f(hv));
            }
        }
    }
    __syncthreads();

    // ---------- phase 3: u @ W_b
    for (int s = 0; s < 4; ++s)
        for (int ct = 0; ct < 2; ++ct) acc[s][ct] = (f32x4){0, 0, 0, 0};
#pragma unroll 1
    for (int ks = 0; ks < 4; ++ks) {
        const int fB = (wave * 8 + ks * 2) * 512 + lane * 8;
        short8 wh0 = *(const short8*)&WBhi[fB];
        short8 wl0 = *(const short8*)&WBlo[fB];
        short8 wh1 = *(const short8*)&WBhi[fB + 512];
        short8 wl1 = *(const short8*)&WBlo[fB + 512];
        const int wo = ks * 32 + quad * 8;
#pragma unroll
        for (int s = 0; s < 4; ++s) {
            const int r = s * 16 + m;
            short8 zh = *(const short8*)&Zhi[r * 136 + wo];
            short8 zl = *(const short8*)&Zlo[r * 136 + wo];
            acc[s][0] = __builtin_amdgcn_mfma_f32_16x16x32_bf16(zh, wh0, acc[s][0], 0, 0, 0);
            acc[s][0] = __builtin_amdgcn_mfma_f32_16x16x32_bf16(zh, wl0, acc[s][0], 0, 0, 0);
            acc[s][0] = __builtin_amdgcn_mfma_f32_16x16x32_bf16(zl, wh0, acc[s][0], 0, 0, 0);
            acc[s][1] = __builtin_amdgcn_mfma_f32_16x16x32_bf16(zh, wh1, acc[s][1], 0, 0, 0);
            acc[s][1] = __builtin_amdgcn_mfma_f32_16x16x32_bf16(zh, wl1, acc[s][1], 0, 0, 0);
            acc[s][1] = __builtin_amdgcn_mfma_f32_16x16x32_bf16(zl, wh1, acc[s][1], 0, 0, 0);
        }
    }

    if (!HEAD) {
        // ---------- h = relu(acc + bb) -> LDS (fp16) -> coalesced global
        __syncthreads();   // phase-3 LDS reads done; reuse Zhi as fp16
        _Float16* Uh = (_Float16*)Zhi;   // 64 x 136 fp16
        for (int s = 0; s < 4; ++s) {
            for (int ct = 0; ct < 2; ++ct) {
                int c = wave * 32 + ct * 16 + m;
                float bbc = bb[c];
                for (int i = 0; i < 4; ++i) {
                    int r = s * 16 + quad * 4 + i;
                    Uh[r * 136 + c] = (_Float16)fmaxf(acc[s][ct][i] + bbc, 0.0f);
                }
            }
        }
        __syncthreads();
        _Float16* hout = (_Float16*)outp;
        const int quart = lane >> 4, l16 = lane & 15;
        for (int g = 0; g < 4; ++g) {
            int r = wave * 16 + g * 4 + quart;
            int node = row0 + r;
            if (node < N_NODES) {
                hv8 v = *(hv8*)&Uh[r * 136 + l16 * 8];
                ((hv8*)hout)[(size_t)node * 16 + l16] = v;
            }
        }
    } else {
        __syncthreads();   // all u reads done; safe to overwrite LDS

        // ---------- h = relu(acc + bb) -> LDS bf16 hi/lo
        for (int s = 0; s < 4; ++s) {
            for (int ct = 0; ct < 2; ++ct) {
                int c = wave * 32 + ct * 16 + m;
                float bbc = bb[c];
                for (int i = 0; i < 4; ++i) {
                    int r = s * 16 + quad * 4 + i;
                    float v = fmaxf(acc[s][ct][i] + bbc, 0.0f);
                    unsigned short hv = f2bf(v);
                    Zhi[r * 136 + c] = hv;
                    Zlo[r * 136 + c] = f2bf(v - bf2f(hv));
                }
            }
        }
        __syncthreads();

        // ---------- phase 4: h @ W_h1 (128 -> 64), fragment-major, streamed
        f32x4 a3[4];
        for (int s = 0; s < 4; ++s) a3[s] = (f32x4){0, 0, 0, 0};
#pragma unroll 1
        for (int ks = 0; ks < 4; ++ks) {
            const int fH = (wave * 4 + ks) * 512 + lane * 8;
            short8 hh = *(const short8*)&WHhi[fH];
            short8 hl = *(const short8*)&WHlo[fH];
            const int wo = ks * 32 + quad * 8;
#pragma unroll
            for (int s = 0; s < 4; ++s) {
                const int r = s * 16 + m;
                short8 zh = *(const short8*)&Zhi[r * 136 + wo];
                short8 zl = *(const short8*)&Zlo[r * 136 + wo];
                a3[s] = __builtin_amdgcn_mfma_f32_16x16x32_bf16(zh, hh, a3[s], 0, 0, 0);
                a3[s] = __builtin_amdgcn_mfma_f32_16x16x32_bf16(zh, hl, a3[s], 0, 0, 0);
                a3[s] = __builtin_amdgcn_mfma_f32_16x16x32_bf16(zl, hh, a3[s], 0, 0, 0);
            }
        }
        __syncthreads();   // phase-4 reads done; reuse LDS as fp32

        float* Hid = (float*)Zhi;   // 64 x 68 fp32 = 17,408 B (fits in Zhi)
        for (int s = 0; s < 4; ++s) {
            int c = wave * 16 + m;
            float bc = bh1[c];
            for (int i = 0; i < 4; ++i) {
                int r = s * 16 + quad * 4 + i;
                Hid[r * 68 + c] = fmaxf(a3[s][i] + bc, 0.0f);
            }
        }
        __syncthreads();

        // ---------- phase 5: hid @ W_h2 (64 -> 2) + b2 -> out
        float* Red = (float*)Zlo;   // 256 floats (Zlo free after phase 4)
        {
            int pair = t >> 1, seg = t & 1;
            int r = pair >> 1, col = pair & 1;
            float p = 0.0f;
#pragma unroll
            for (int j = seg * 32; j < seg * 32 + 32; ++j)
                p += Hid[r * 68 + j] * W2[j * 2 + col];
            Red[t] = p;
        }
        __syncthreads();
        if (t < 128) {
            float* outF = (float*)outp;
            int r = t >> 1, col = t & 1;
            float a = b2[col] + (Red[t * 2] + Red[t * 2 + 1]);
            int node = row0 + r;
            if (node < N_NODES) outF[(size_t)node * 2 + col] = a;
        }
    }
}

// ------------------------------------------------------------------ launch

extern "C" void kernel_launch(void* const* d_in, const int* in_sizes, int n_in,
                              void* d_out, int out_size, void* d_ws, size_t ws_size,
                              hipStream_t stream) {
    const float* x    = (const float*)d_in[0];
    const int*   ei   = (const int*)d_in[1];
    const float* eps  = (const float*)d_in[2];
    const float* W_a  = (const float*)d_in[3];
    const float* b_a  = (const float*)d_in[4];
    const float* W_b  = (const float*)d_in[5];
    const float* b_b  = (const float*)d_in[6];
    const float* W_h1 = (const float*)d_in[7];
    const float* b_h1 = (const float*)d_in[8];
    const float* W_h2 = (const float*)d_in[9];
    const float* b_h2 = (const float*)d_in[10];
    float* out = (float*)d_out;

    const int N = N_NODES, E = N_EDGES;
    const int* src = ei;
    const int* dst = ei + E;

    char* ws = (char*)d_ws;
    size_t off = 0;
    auto carve = [&](size_t bytes) {
        char* p = ws + off;
        off = (off + bytes + 255) & ~(size_t)255;
        return p;
    };
    _Float16* xh   = (_Float16*)carve((size_t)N * HID * sizeof(_Float16));
    _Float16* zb   = (_Float16*)carve((size_t)N * HID * sizeof(_Float16));
    _Float16* bufA = (_Float16*)carve((size_t)N * HID * sizeof(_Float16));
    _Float16* bufB = (_Float16*)carve((size_t)N * HID * sizeof(_Float16));
    int*   tmp    = (int*)carve((size_t)E * sizeof(int));
    int*   csr    = (int*)carve((size_t)E * sizeof(int));
    int*   offs   = (int*)carve((size_t)(N + 1) * sizeof(int));
    int*   bh     = (int*)carve((size_t)NB * NBLK * sizeof(int));
    int*   bhs    = (int*)carve((size_t)NB * NBLK * sizeof(int));
    int*   gsum   = (int*)carve(256 * sizeof(int));
    unsigned short* whi = (unsigned short*)carve(7 * 16384 * sizeof(unsigned short));
    unsigned short* wlo = (unsigned short*)carve(7 * 16384 * sizeof(unsigned short));
    (void)ws_size;

    // ---- single cooperative build + convert kernel
    {
        void* bargs[] = {(void*)&src, (void*)&dst, (void*)&bh, (void*)&gsum,
                         (void*)&bhs, (void*)&tmp, (void*)&offs, (void*)&csr,
                         (void*)&x, (void*)&xh, (void*)&W_a, (void*)&W_b,
                         (void*)&W_h1, (void*)&whi, (void*)&wlo};
        hipLaunchCooperativeKernel((void*)build_k, dim3(NBLK), dim3(256),
                                   bargs, 0, stream);
    }

    const int agg_grid = (N + 15) / 16;
    const int mlp_grid = (N + 63) / 64;
    #define WSLOT(s) (whi + (s) * 16384), (wlo + (s) * 16384)
    #define NOHEAD (const unsigned short*)nullptr, (const unsigned short*)nullptr, \
                   (const float*)nullptr, (const float*)nullptr, (const float*)nullptr

    // layer 0
    agg16_k<<<agg_grid, 256, 0, stream>>>(xh, offs, csr, eps, 0, zb);
    mlp_k<false><<<mlp_grid, 256, 0, stream>>>(zb, WSLOT(0), b_a + 0 * 128,
        WSLOT(1), b_b + 0 * 128, NOHEAD, (void*)bufA);
    // layer 1
    agg16_k<<<agg_grid, 256, 0, stream>>>(bufA, offs, csr, eps, 1, zb);
    mlp_k<false><<<mlp_grid, 256, 0, stream>>>(zb, WSLOT(2), b_a + 1 * 128,
        WSLOT(3), b_b + 1 * 128, NOHEAD, (void*)bufB);
    // layer 2 + head
    agg16_k<<<agg_grid, 256, 0, stream>>>(bufB, offs, csr, eps, 2, zb);
    mlp_k<true><<<mlp_grid, 256, 0, stream>>>(zb, WSLOT(4), b_a + 2 * 128,
        WSLOT(5), b_b + 2 * 128, WSLOT(6), b_h1, W_h2, b_h2, (void*)out);
}

// Round 14
// 270.541 us; speedup vs baseline: 1.4971x; 1.4971x over previous
//
#include <hip/hip_runtime.h>
#include <hip/hip_bf16.h>

#define N_NODES 50000
#define N_EDGES 800000
#define HID 128

#define NB 391      // dst buckets: dst>>7, 128 nodes each
#define NBLK 160    // histogram/scatter blocks
#define EPB 5000    // edges per block (NBLK*EPB == N_EDGES)

typedef __attribute__((ext_vector_type(8))) short short8;     // 8 bf16 (4 VGPR)
typedef __attribute__((ext_vector_type(4))) float f32x4;      // MFMA acc
typedef __attribute__((ext_vector_type(4))) unsigned short us4;
typedef _Float16 hv8 __attribute__((ext_vector_type(8)));     // 8 fp16 (16 B)
typedef _Float16 hv4 __attribute__((ext_vector_type(4)));     // 4 fp16 (8 B)

__device__ __forceinline__ unsigned short f2bf(float v) {
    union { float f; unsigned u; } x; x.f = v;
    unsigned r = x.u + 0x7fff + ((x.u >> 16) & 1);   // RTN-even
    return (unsigned short)(r >> 16);
}
__device__ __forceinline__ float bf2f(unsigned short b) {
    union { unsigned u; float f; } x; x.u = ((unsigned)b) << 16;
    return x.f;
}

// ----------------------------- CSR build: streaming 2-level counting sort
// (R12 split-chain form: thousands of blocks per phase. R13's cooperative
// single-kernel variant capped memory parallelism at 160 co-resident blocks
// -> 294 GB/s -> 166 us. Do NOT merge these into a cooperative grid.)

__global__ __launch_bounds__(256)
void hist_k(const int* __restrict__ dst, int* __restrict__ bh, int E) {
    __shared__ int h[NB];
    for (int i = threadIdx.x; i < NB; i += 256) h[i] = 0;
    __syncthreads();
    const int base = blockIdx.x * EPB;
    const int end = min(base + EPB, E);
    for (int i = base + threadIdx.x; i < end; i += 256)
        atomicAdd(&h[dst[i] >> 7], 1);
    __syncthreads();
    for (int i = threadIdx.x; i < NB; i += 256)
        bh[i * NBLK + blockIdx.x] = h[i];
}

// scanA: per-block sums of 2048-int chunks -> bsum[31]
__global__ __launch_bounds__(256)
void scanA_k(const int* __restrict__ in, int* __restrict__ bsum, int n) {
    const int t = threadIdx.x, base = blockIdx.x * 2048 + t * 8;
    int s = 0;
#pragma unroll
    for (int k = 0; k < 8; ++k) s += (base + k < n) ? in[base + k] : 0;
    __shared__ int sh[256];
    sh[t] = s;
    __syncthreads();
    for (int o = 128; o > 0; o >>= 1) {
        if (t < o) sh[t] += sh[t + o];
        __syncthreads();
    }
    if (t == 0) bsum[blockIdx.x] = sh[0];
}

// scanC: each block self-scans the (<=64) partials, then local scan + write
__global__ __launch_bounds__(256)
void scanC_k(const int* __restrict__ in, const int* __restrict__ bsum,
             int* __restrict__ out, int n, int B) {
    const int t = threadIdx.x, base = blockIdx.x * 2048 + t * 8;
    __shared__ int blockoff;
    if (t == 0) {
        int p = 0;
        for (int i = 0; i < blockIdx.x; ++i) p += bsum[i];   // B<=64, trivial
        blockoff = p;
    }
    int v[8]; int s = 0;
#pragma unroll
    for (int k = 0; k < 8; ++k) { v[k] = (base + k < n) ? in[base + k] : 0; s += v[k]; }
    __shared__ int sh[256];
    sh[t] = s;
    __syncthreads();
    for (int o = 1; o < 256; o <<= 1) {
        int u = (t >= o) ? sh[t - o] : 0;
        __syncthreads();
        sh[t] += u;
        __syncthreads();
    }
    int run = ((t == 0) ? 0 : sh[t - 1]) + blockoff;
#pragma unroll
    for (int k = 0; k < 8; ++k) {
        if (base + k < n) out[base + k] = run;
        run += v[k];
    }
}

// scatter: edges -> bucket-segmented tmp (packed: src<<7 | dst&127)
__global__ __launch_bounds__(256)
void scatter_k(const int* __restrict__ src, const int* __restrict__ dst,
               const int* __restrict__ bhs, int* __restrict__ tmp, int E) {
    __shared__ int cur[NB];
    for (int i = threadIdx.x; i < NB; i += 256) cur[i] = bhs[i * NBLK + blockIdx.x];
    __syncthreads();
    const int base = blockIdx.x * EPB;
    const int end = min(base + EPB, E);
    for (int i = base + threadIdx.x; i < end; i += 256) {
        int d = dst[i];
        int p = atomicAdd(&cur[d >> 7], 1);
        tmp[p] = (src[i] << 7) | (d & 127);
    }
}

// bucket: one block per bucket — 128-counter local sort; writes offs + csr
__global__ __launch_bounds__(256)
void bucket_k(const int* __restrict__ tmp, const int* __restrict__ bhs,
              int* __restrict__ offs, int* __restrict__ csr, int E, int N) {
    const int b = blockIdx.x;
    const int t = threadIdx.x;
    __shared__ int hist[128], excl[128], cur[128];
    const int bstart = bhs[b * NBLK];
    const int bend = (b + 1 < NB) ? bhs[(b + 1) * NBLK] : E;
    if (t < 128) hist[t] = 0;
    __syncthreads();
    for (int i = bstart + t; i < bend; i += 256)
        atomicAdd(&hist[tmp[i] & 127], 1);
    __syncthreads();
    if (t < 128) excl[t] = hist[t];
    __syncthreads();
    for (int o = 1; o < 128; o <<= 1) {
        int u = (t < 128 && t >= o) ? excl[t - o] : 0;
        __syncthreads();
        if (t < 128) excl[t] += u;
        __syncthreads();
    }
    const int node0 = b * 128;
    if (t < 128) {
        int base = bstart + ((t == 0) ? 0 : excl[t - 1]);
        if (node0 + t < N) offs[node0 + t] = base;
        cur[t] = base;
    }
    if (b == 0 && t == 0) offs[N] = E;
    __syncthreads();
    for (int i = bstart + t; i < bend; i += 256) {
        int e = tmp[i];
        int p = atomicAdd(&cur[e & 127], 1);
        csr[p] = e >> 7;
    }
}

// ------------------------- merged converts: x -> fp16, weights -> bf16 hi/lo
// W output is FRAGMENT-MAJOR (verified R12): for 128-col mats, element (k,n)
// lands at ((w*8 + ks*2 + ct)*64 + quad*16 + m)*8 + j with n = w*32+ct*16+m,
// k = ks*32 + quad*8 + j -> each W fragment is one contiguous 1 KB wave-load.
// W_h1 (64 cols): ((w*4 + ks)*64 + quad*16 + m)*8 + j, n = w*16+m.
#define XB 6250     // ceil(1600000/256)
#define WB 416      // ceil(106496/256)
__global__ __launch_bounds__(256)
void cvt_k(const float* __restrict__ x, _Float16* __restrict__ xh,
           const float* __restrict__ Wa, const float* __restrict__ Wb,
           const float* __restrict__ Wh1,
           unsigned short* __restrict__ whi, unsigned short* __restrict__ wlo) {
    if (blockIdx.x < XB) {
        int i = blockIdx.x * 256 + threadIdx.x;
        if (i < 1600000) {
            float4 v = *(const float4*)&x[i * 4];
            hv4 o;
            o.x = (_Float16)v.x; o.y = (_Float16)v.y;
            o.z = (_Float16)v.z; o.w = (_Float16)v.w;
            *(hv4*)&xh[i * 4] = o;
        }
        return;
    }
    int id = (blockIdx.x - XB) * 256 + threadIdx.x;
    float v; int dst;
    if (id < 98304) {                      // 3 x W_a then 3 x W_b (128x128)
        int isB = (id >= 49152);
        int id2 = isB ? id - 49152 : id;
        int l = id2 >> 14, e = id2 & 16383;
        v = isB ? Wb[id2] : Wa[id2];
        int k = e >> 7, n = e & 127;
        int w = n >> 5, ct = (n >> 4) & 1, m = n & 15;
        int ks = k >> 5, quad = (k >> 3) & 3, j = k & 7;
        int within = ((w * 8 + ks * 2 + ct) * 64 + quad * 16 + m) * 8 + j;
        dst = (2 * l + isB) * 16384 + within;
    } else if (id < 106496) {              // W_h1 [128][64]
        int e = id - 98304;
        v = Wh1[e];
        int k = e >> 6, n = e & 63;
        int w = n >> 4, m = n & 15;
        int ks = k >> 5, quad = (k >> 3) & 3, j = k & 7;
        dst = 6 * 16384 + ((w * 4 + ks) * 64 + quad * 16 + m) * 8 + j;
    } else return;
    unsigned short hi = f2bf(v);
    whi[dst] = hi;
    wlo[dst] = f2bf(v - bf2f(hi));
}

// ------------------------------------------- standalone gather-aggregate
// Pure gather kernel: 16 nodes per 256-block, one quarter-wave
// (16 lanes x hv8 = full 256 B row) per node, unroll-4.
__global__ __launch_bounds__(256)
void agg16_k(const _Float16* __restrict__ h_in,
             const int* __restrict__ offs, const int* __restrict__ csr,
             const float* __restrict__ eps, int layer,
             _Float16* __restrict__ z) {
    const int qw = threadIdx.x >> 4;           // 0..15
    const int l16 = threadIdx.x & 15;
    const int node = blockIdx.x * 16 + qw;
    if (node >= N_NODES) return;
    const hv8* __restrict__ h8 = (const hv8*)h_in;   // row = 16 hv8
    const float sc = 1.0f + eps[layer];
    const int beg = offs[node], end = offs[node + 1];
    float a0[8] = {0,0,0,0,0,0,0,0};
    float a1[8] = {0,0,0,0,0,0,0,0};
    int j = beg;
    for (; j + 4 <= end; j += 4) {
        int s0 = csr[j], s1 = csr[j+1], s2 = csr[j+2], s3 = csr[j+3];
        hv8 v0 = h8[(size_t)s0 * 16 + l16];
        hv8 v1 = h8[(size_t)s1 * 16 + l16];
        hv8 v2 = h8[(size_t)s2 * 16 + l16];
        hv8 v3 = h8[(size_t)s3 * 16 + l16];
#pragma unroll
        for (int e = 0; e < 8; ++e) {
            a0[e] += (float)v0[e] + (float)v2[e];
            a1[e] += (float)v1[e] + (float)v3[e];
        }
    }
    for (; j < end; ++j) {
        hv8 v = h8[(size_t)csr[j] * 16 + l16];
#pragma unroll
        for (int e = 0; e < 8; ++e) a0[e] += (float)v[e];
    }
    hv8 self = h8[(size_t)node * 16 + l16];
    hv8 o;
#pragma unroll
    for (int e = 0; e < 8; ++e)
        o[e] = (_Float16)(sc * (float)self[e] + (a0[e] + a1[e]));
    ((hv8*)z)[(size_t)node * 16 + l16] = o;
}

// ------------------------------------------------------- MLP kernel (v4)
// One block = 64 rows (grid 782). Fragment-major W, streamed per k-step.
// !HEAD h-store goes through LDS restage -> coalesced hv8 global stores.
// FP accumulate order per acc element unchanged (ks ascending).
template <bool HEAD>
__global__ __launch_bounds__(256)
void mlp_k(const _Float16* __restrict__ z_in,
           const unsigned short* __restrict__ WAhi, const unsigned short* __restrict__ WAlo,
           const float* __restrict__ ba,
           const unsigned short* __restrict__ WBhi, const unsigned short* __restrict__ WBlo,
           const float* __restrict__ bb,
           const unsigned short* __restrict__ WHhi, const unsigned short* __restrict__ WHlo,
           const float* __restrict__ bh1,
           const float* __restrict__ W2, const float* __restrict__ b2,
           void* __restrict__ outp) {
    __shared__ unsigned short Zhi[64 * 136];   // 17,408 B
    __shared__ unsigned short Zlo[64 * 136];
    const int t = threadIdx.x;
    const int wave = t >> 6, lane = t & 63;
    const int m = lane & 15, quad = lane >> 4;
    const int row0 = blockIdx.x * 64;

    // ---------- stage z -> LDS bf16 hi/lo (coalesced hv8 reads)
    {
        const int quart = lane >> 4, l16 = lane & 15;
        const hv8* __restrict__ z8 = (const hv8*)z_in;
        for (int g = 0; g < 4; ++g) {
            const int r = wave * 16 + g * 4 + quart;
            const int node = row0 + r;
            float o[8] = {0,0,0,0,0,0,0,0};
            if (node < N_NODES) {
                hv8 v = z8[(size_t)node * 16 + l16];
#pragma unroll
                for (int e = 0; e < 8; ++e) o[e] = (float)v[e];
            }
            us4 hi0, hi1, lo0, lo1;
#pragma unroll
            for (int e = 0; e < 4; ++e) {
                hi0[e] = f2bf(o[e]);     lo0[e] = f2bf(o[e]     - bf2f(hi0[e]));
                hi1[e] = f2bf(o[e + 4]); lo1[e] = f2bf(o[e + 4] - bf2f(hi1[e]));
            }
            *(us4*)&Zhi[r * 136 + l16 * 8]     = hi0;
            *(us4*)&Zhi[r * 136 + l16 * 8 + 4] = hi1;
            *(us4*)&Zlo[r * 136 + l16 * 8]     = lo0;
            *(us4*)&Zlo[r * 136 + l16 * 8 + 4] = lo1;
        }
    }
    __syncthreads();

    // ---------- phase 2: z @ W_a (fragment-major W, streamed per ks)
    f32x4 acc[4][2];
    for (int s = 0; s < 4; ++s)
        for (int ct = 0; ct < 2; ++ct) acc[s][ct] = (f32x4){0, 0, 0, 0};
#pragma unroll 1
    for (int ks = 0; ks < 4; ++ks) {
        const int fA = (wave * 8 + ks * 2) * 512 + lane * 8;
        short8 wh0 = *(const short8*)&WAhi[fA];
        short8 wl0 = *(const short8*)&WAlo[fA];
        short8 wh1 = *(const short8*)&WAhi[fA + 512];
        short8 wl1 = *(const short8*)&WAlo[fA + 512];
        const int wo = ks * 32 + quad * 8;
#pragma unroll
        for (int s = 0; s < 4; ++s) {
            const int r = s * 16 + m;
            short8 zh = *(const short8*)&Zhi[r * 136 + wo];
            short8 zl = *(const short8*)&Zlo[r * 136 + wo];
            acc[s][0] = __builtin_amdgcn_mfma_f32_16x16x32_bf16(zh, wh0, acc[s][0], 0, 0, 0);
            acc[s][0] = __builtin_amdgcn_mfma_f32_16x16x32_bf16(zh, wl0, acc[s][0], 0, 0, 0);
            acc[s][0] = __builtin_amdgcn_mfma_f32_16x16x32_bf16(zl, wh0, acc[s][0], 0, 0, 0);
            acc[s][1] = __builtin_amdgcn_mfma_f32_16x16x32_bf16(zh, wh1, acc[s][1], 0, 0, 0);
            acc[s][1] = __builtin_amdgcn_mfma_f32_16x16x32_bf16(zh, wl1, acc[s][1], 0, 0, 0);
            acc[s][1] = __builtin_amdgcn_mfma_f32_16x16x32_bf16(zl, wh1, acc[s][1], 0, 0, 0);
        }
    }
    __syncthreads();   // all z reads done; safe to overwrite LDS

    // ---------- u = relu(acc + ba) -> LDS bf16 hi/lo
    for (int s = 0; s < 4; ++s) {
        for (int ct = 0; ct < 2; ++ct) {
            int c = wave * 32 + ct * 16 + m;
            float bac = ba[c];
            for (int i = 0; i < 4; ++i) {
                int r = s * 16 + quad * 4 + i;
                float v = fmaxf(acc[s][ct][i] + bac, 0.0f);
                unsigned short hv = f2bf(v);
                Zhi[r * 136 + c] = hv;
                Zlo[r * 136 + c] = f2bf(v - bf2f(hv));
            }
        }
    }
    __syncthreads();

    // ---------- phase 3: u @ W_b
    for (int s = 0; s < 4; ++s)
        for (int ct = 0; ct < 2; ++ct) acc[s][ct] = (f32x4){0, 0, 0, 0};
#pragma unroll 1
    for (int ks = 0; ks < 4; ++ks) {
        const int fB = (wave * 8 + ks * 2) * 512 + lane * 8;
        short8 wh0 = *(const short8*)&WBhi[fB];
        short8 wl0 = *(const short8*)&WBlo[fB];
        short8 wh1 = *(const short8*)&WBhi[fB + 512];
        short8 wl1 = *(const short8*)&WBlo[fB + 512];
        const int wo = ks * 32 + quad * 8;
#pragma unroll
        for (int s = 0; s < 4; ++s) {
            const int r = s * 16 + m;
            short8 zh = *(const short8*)&Zhi[r * 136 + wo];
            short8 zl = *(const short8*)&Zlo[r * 136 + wo];
            acc[s][0] = __builtin_amdgcn_mfma_f32_16x16x32_bf16(zh, wh0, acc[s][0], 0, 0, 0);
            acc[s][0] = __builtin_amdgcn_mfma_f32_16x16x32_bf16(zh, wl0, acc[s][0], 0, 0, 0);
            acc[s][0] = __builtin_amdgcn_mfma_f32_16x16x32_bf16(zl, wh0, acc[s][0], 0, 0, 0);
            acc[s][1] = __builtin_amdgcn_mfma_f32_16x16x32_bf16(zh, wh1, acc[s][1], 0, 0, 0);
            acc[s][1] = __builtin_amdgcn_mfma_f32_16x16x32_bf16(zh, wl1, acc[s][1], 0, 0, 0);
            acc[s][1] = __builtin_amdgcn_mfma_f32_16x16x32_bf16(zl, wh1, acc[s][1], 0, 0, 0);
        }
    }

    if (!HEAD) {
        // ---------- h = relu(acc + bb) -> LDS (fp16) -> coalesced global
        __syncthreads();   // phase-3 LDS reads done; reuse Zhi as fp16
        _Float16* Uh = (_Float16*)Zhi;   // 64 x 136 fp16
        for (int s = 0; s < 4; ++s) {
            for (int ct = 0; ct < 2; ++ct) {
                int c = wave * 32 + ct * 16 + m;
                float bbc = bb[c];
                for (int i = 0; i < 4; ++i) {
                    int r = s * 16 + quad * 4 + i;
                    Uh[r * 136 + c] = (_Float16)fmaxf(acc[s][ct][i] + bbc, 0.0f);
                }
            }
        }
        __syncthreads();
        _Float16* hout = (_Float16*)outp;
        const int quart = lane >> 4, l16 = lane & 15;
        for (int g = 0; g < 4; ++g) {
            int r = wave * 16 + g * 4 + quart;
            int node = row0 + r;
            if (node < N_NODES) {
                hv8 v = *(hv8*)&Uh[r * 136 + l16 * 8];
                ((hv8*)hout)[(size_t)node * 16 + l16] = v;
            }
        }
    } else {
        __syncthreads();   // all u reads done; safe to overwrite LDS

        // ---------- h = relu(acc + bb) -> LDS bf16 hi/lo
        for (int s = 0; s < 4; ++s) {
            for (int ct = 0; ct < 2; ++ct) {
                int c = wave * 32 + ct * 16 + m;
                float bbc = bb[c];
                for (int i = 0; i < 4; ++i) {
                    int r = s * 16 + quad * 4 + i;
                    float v = fmaxf(acc[s][ct][i] + bbc, 0.0f);
                    unsigned short hv = f2bf(v);
                    Zhi[r * 136 + c] = hv;
                    Zlo[r * 136 + c] = f2bf(v - bf2f(hv));
                }
            }
        }
        __syncthreads();

        // ---------- phase 4: h @ W_h1 (128 -> 64), fragment-major, streamed
        f32x4 a3[4];
        for (int s = 0; s < 4; ++s) a3[s] = (f32x4){0, 0, 0, 0};
#pragma unroll 1
        for (int ks = 0; ks < 4; ++ks) {
            const int fH = (wave * 4 + ks) * 512 + lane * 8;
            short8 hh = *(const short8*)&WHhi[fH];
            short8 hl = *(const short8*)&WHlo[fH];
            const int wo = ks * 32 + quad * 8;
#pragma unroll
            for (int s = 0; s < 4; ++s) {
                const int r = s * 16 + m;
                short8 zh = *(const short8*)&Zhi[r * 136 + wo];
                short8 zl = *(const short8*)&Zlo[r * 136 + wo];
                a3[s] = __builtin_amdgcn_mfma_f32_16x16x32_bf16(zh, hh, a3[s], 0, 0, 0);
                a3[s] = __builtin_amdgcn_mfma_f32_16x16x32_bf16(zh, hl, a3[s], 0, 0, 0);
                a3[s] = __builtin_amdgcn_mfma_f32_16x16x32_bf16(zl, hh, a3[s], 0, 0, 0);
            }
        }
        __syncthreads();   // phase-4 reads done; reuse LDS as fp32

        float* Hid = (float*)Zhi;   // 64 x 68 fp32 = 17,408 B (fits in Zhi)
        for (int s = 0; s < 4; ++s) {
            int c = wave * 16 + m;
            float bc = bh1[c];
            for (int i = 0; i < 4; ++i) {
                int r = s * 16 + quad * 4 + i;
                Hid[r * 68 + c] = fmaxf(a3[s][i] + bc, 0.0f);
            }
        }
        __syncthreads();

        // ---------- phase 5: hid @ W_h2 (64 -> 2) + b2 -> out
        float* Red = (float*)Zlo;   // 256 floats (Zlo free after phase 4)
        {
            int pair = t >> 1, seg = t & 1;
            int r = pair >> 1, col = pair & 1;
            float p = 0.0f;
#pragma unroll
            for (int j = seg * 32; j < seg * 32 + 32; ++j)
                p += Hid[r * 68 + j] * W2[j * 2 + col];
            Red[t] = p;
        }
        __syncthreads();
        if (t < 128) {
            float* outF = (float*)outp;
            int r = t >> 1, col = t & 1;
            float a = b2[col] + (Red[t * 2] + Red[t * 2 + 1]);
            int node = row0 + r;
            if (node < N_NODES) outF[(size_t)node * 2 + col] = a;
        }
    }
}

// ------------------------------------------------------------------ launch

extern "C" void kernel_launch(void* const* d_in, const int* in_sizes, int n_in,
                              void* d_out, int out_size, void* d_ws, size_t ws_size,
                              hipStream_t stream) {
    const float* x    = (const float*)d_in[0];
    const int*   ei   = (const int*)d_in[1];
    const float* eps  = (const float*)d_in[2];
    const float* W_a  = (const float*)d_in[3];
    const float* b_a  = (const float*)d_in[4];
    const float* W_b  = (const float*)d_in[5];
    const float* b_b  = (const float*)d_in[6];
    const float* W_h1 = (const float*)d_in[7];
    const float* b_h1 = (const float*)d_in[8];
    const float* W_h2 = (const float*)d_in[9];
    const float* b_h2 = (const float*)d_in[10];
    float* out = (float*)d_out;

    const int N = N_NODES, E = N_EDGES;
    const int* src = ei;
    const int* dst = ei + E;

    char* ws = (char*)d_ws;
    size_t off = 0;
    auto carve = [&](size_t bytes) {
        char* p = ws + off;
        off = (off + bytes + 255) & ~(size_t)255;
        return p;
    };
    _Float16* xh   = (_Float16*)carve((size_t)N * HID * sizeof(_Float16));
    _Float16* zb   = (_Float16*)carve((size_t)N * HID * sizeof(_Float16));
    _Float16* bufA = (_Float16*)carve((size_t)N * HID * sizeof(_Float16));
    _Float16* bufB = (_Float16*)carve((size_t)N * HID * sizeof(_Float16));
    int*   tmp    = (int*)carve((size_t)E * sizeof(int));
    int*   csr    = (int*)carve((size_t)E * sizeof(int));
    int*   offs   = (int*)carve((size_t)(N + 1) * sizeof(int));
    int*   bh     = (int*)carve((size_t)NB * NBLK * sizeof(int));
    int*   bhs    = (int*)carve((size_t)NB * NBLK * sizeof(int));
    int*   bsum   = (int*)carve(64 * sizeof(int));
    unsigned short* whi = (unsigned short*)carve(7 * 16384 * sizeof(unsigned short));
    unsigned short* wlo = (unsigned short*)carve(7 * 16384 * sizeof(unsigned short));
    (void)ws_size;

    // ---- CSR build: streaming counting sort (LDS atomics only)
    const int M = NB * NBLK;                     // 62,560
    const int SB = (M + 2047) / 2048;            // 31 scan blocks
    hist_k<<<NBLK, 256, 0, stream>>>(dst, bh, E);
    scanA_k<<<SB, 256, 0, stream>>>(bh, bsum, M);
    scanC_k<<<SB, 256, 0, stream>>>(bh, bsum, bhs, M, SB);
    scatter_k<<<NBLK, 256, 0, stream>>>(src, dst, bhs, tmp, E);
    bucket_k<<<NB, 256, 0, stream>>>(tmp, bhs, offs, csr, E, N);

    // ---- merged input + weight conversion (fragment-major W)
    cvt_k<<<XB + WB, 256, 0, stream>>>(x, xh, W_a, W_b, W_h1, whi, wlo);

    const int agg_grid = (N + 15) / 16;
    const int mlp_grid = (N + 63) / 64;
    #define WSLOT(s) (whi + (s) * 16384), (wlo + (s) * 16384)
    #define NOHEAD (const unsigned short*)nullptr, (const unsigned short*)nullptr, \
                   (const float*)nullptr, (const float*)nullptr, (const float*)nullptr

    // layer 0
    agg16_k<<<agg_grid, 256, 0, stream>>>(xh, offs, csr, eps, 0, zb);
    mlp_k<false><<<mlp_grid, 256, 0, stream>>>(zb, WSLOT(0), b_a + 0 * 128,
        WSLOT(1), b_b + 0 * 128, NOHEAD, (void*)bufA);
    // layer 1
    agg16_k<<<agg_grid, 256, 0, stream>>>(bufA, offs, csr, eps, 1, zb);
    mlp_k<false><<<mlp_grid, 256, 0, stream>>>(zb, WSLOT(2), b_a + 1 * 128,
        WSLOT(3), b_b + 1 * 128, NOHEAD, (void*)bufB);
    // layer 2 + head
    agg16_k<<<agg_grid, 256, 0, stream>>>(bufB, offs, csr, eps, 2, zb);
    mlp_k<true><<<mlp_grid, 256, 0, stream>>>(zb, WSLOT(4), b_a + 2 * 128,
        WSLOT(5), b_b + 2 * 128, WSLOT(6), b_h1, W_h2, b_h2, (void*)out);
}

// Round 15
// 269.920 us; speedup vs baseline: 1.5005x; 1.0023x over previous
//
#include <hip/hip_runtime.h>
#include <hip/hip_bf16.h>

#define N_NODES 50000
#define N_EDGES 800000
#define HID 128

#define NB 391      // dst buckets: dst>>7, 128 nodes each
#define NBLK 160    // histogram/scatter blocks
#define EPB 5000    // edges per block (NBLK*EPB == N_EDGES)

typedef __attribute__((ext_vector_type(8))) short short8;     // 8 bf16 (4 VGPR)
typedef __attribute__((ext_vector_type(4))) float f32x4;      // MFMA acc
typedef __attribute__((ext_vector_type(4))) unsigned short us4;
typedef _Float16 hv8 __attribute__((ext_vector_type(8)));     // 8 fp16 (16 B)
typedef _Float16 hv4 __attribute__((ext_vector_type(4)));     // 4 fp16 (8 B)

__device__ __forceinline__ unsigned short f2bf(float v) {
    union { float f; unsigned u; } x; x.f = v;
    unsigned r = x.u + 0x7fff + ((x.u >> 16) & 1);   // RTN-even
    return (unsigned short)(r >> 16);
}
__device__ __forceinline__ float bf2f(unsigned short b) {
    union { unsigned u; float f; } x; x.u = ((unsigned)b) << 16;
    return x.f;
}

// -------------------- merged: histogram + converts (independent streaming)
// blocks [0, NBLK): per-block LDS histogram of dst buckets.
// blocks [NBLK, NBLK+6250): x -> fp16.
// blocks [NBLK+6250, NBLK+6666): W -> fragment-major bf16 hi/lo.
// (R13 lesson: do NOT make build phases cooperative — 160 co-resident blocks
// cap memory parallelism at ~300 GB/s. This merge keeps full oversubscription.)
// W fragment-major layout (verified R12): 128-col mats, element (k,n) ->
// ((w*8+ks*2+ct)*64 + quad*16+m)*8 + j with n=w*32+ct*16+m, k=ks*32+quad*8+j;
// W_h1 (64 cols): ((w*4+ks)*64 + quad*16+m)*8 + j, n=w*16+m.
#define CVTXB 6250   // ceil(1600000/256)
#define CVTWB 416    // ceil(106496/256)
__global__ __launch_bounds__(256)
void histcvt_k(const int* __restrict__ dst, int* __restrict__ bh, int E,
               const float* __restrict__ x, _Float16* __restrict__ xh,
               const float* __restrict__ Wa, const float* __restrict__ Wb,
               const float* __restrict__ Wh1,
               unsigned short* __restrict__ whi, unsigned short* __restrict__ wlo) {
    if (blockIdx.x < NBLK) {
        __shared__ int h[NB];
        for (int i = threadIdx.x; i < NB; i += 256) h[i] = 0;
        __syncthreads();
        const int base = blockIdx.x * EPB;
        const int end = min(base + EPB, E);
        for (int i = base + threadIdx.x; i < end; i += 256)
            atomicAdd(&h[dst[i] >> 7], 1);
        __syncthreads();
        for (int i = threadIdx.x; i < NB; i += 256)
            bh[i * NBLK + blockIdx.x] = h[i];
        return;
    }
    int cb = blockIdx.x - NBLK;
    if (cb < CVTXB) {
        int i = cb * 256 + threadIdx.x;
        if (i < 1600000) {
            float4 v = *(const float4*)&x[i * 4];
            hv4 o;
            o.x = (_Float16)v.x; o.y = (_Float16)v.y;
            o.z = (_Float16)v.z; o.w = (_Float16)v.w;
            *(hv4*)&xh[i * 4] = o;
        }
        return;
    }
    int id = (cb - CVTXB) * 256 + threadIdx.x;
    float v; int dsti;
    if (id < 98304) {                      // 3 x W_a then 3 x W_b (128x128)
        int isB = (id >= 49152);
        int id2 = isB ? id - 49152 : id;
        int l = id2 >> 14, e = id2 & 16383;
        v = isB ? Wb[id2] : Wa[id2];
        int k = e >> 7, n = e & 127;
        int w = n >> 5, ct = (n >> 4) & 1, m = n & 15;
        int ks = k >> 5, quad = (k >> 3) & 3, j = k & 7;
        dsti = (2 * l + isB) * 16384 +
               ((w * 8 + ks * 2 + ct) * 64 + quad * 16 + m) * 8 + j;
    } else if (id < 106496) {              // W_h1 [128][64]
        int e = id - 98304;
        v = Wh1[e];
        int k = e >> 6, n = e & 63;
        int w = n >> 4, m = n & 15;
        int ks = k >> 5, quad = (k >> 3) & 3, j = k & 7;
        dsti = 6 * 16384 + ((w * 4 + ks) * 64 + quad * 16 + m) * 8 + j;
    } else return;
    unsigned short hi = f2bf(v);
    whi[dsti] = hi;
    wlo[dsti] = f2bf(v - bf2f(hi));
}

// scanA: per-block sums of 2048-int chunks -> bsum[31]
__global__ __launch_bounds__(256)
void scanA_k(const int* __restrict__ in, int* __restrict__ bsum, int n) {
    const int t = threadIdx.x, base = blockIdx.x * 2048 + t * 8;
    int s = 0;
#pragma unroll
    for (int k = 0; k < 8; ++k) s += (base + k < n) ? in[base + k] : 0;
    __shared__ int sh[256];
    sh[t] = s;
    __syncthreads();
    for (int o = 128; o > 0; o >>= 1) {
        if (t < o) sh[t] += sh[t + o];
        __syncthreads();
    }
    if (t == 0) bsum[blockIdx.x] = sh[0];
}

// scanC: each block self-scans the (<=64) partials, then local scan + write
__global__ __launch_bounds__(256)
void scanC_k(const int* __restrict__ in, const int* __restrict__ bsum,
             int* __restrict__ out, int n, int B) {
    const int t = threadIdx.x, base = blockIdx.x * 2048 + t * 8;
    __shared__ int blockoff;
    if (t == 0) {
        int p = 0;
        for (int i = 0; i < blockIdx.x; ++i) p += bsum[i];   // B<=64, trivial
        blockoff = p;
    }
    int v[8]; int s = 0;
#pragma unroll
    for (int k = 0; k < 8; ++k) { v[k] = (base + k < n) ? in[base + k] : 0; s += v[k]; }
    __shared__ int sh[256];
    sh[t] = s;
    __syncthreads();
    for (int o = 1; o < 256; o <<= 1) {
        int u = (t >= o) ? sh[t - o] : 0;
        __syncthreads();
        sh[t] += u;
        __syncthreads();
    }
    int run = ((t == 0) ? 0 : sh[t - 1]) + blockoff;
#pragma unroll
    for (int k = 0; k < 8; ++k) {
        if (base + k < n) out[base + k] = run;
        run += v[k];
    }
}

// scatter: edges -> bucket-segmented tmp (packed: src<<7 | dst&127)
__global__ __launch_bounds__(256)
void scatter_k(const int* __restrict__ src, const int* __restrict__ dst,
               const int* __restrict__ bhs, int* __restrict__ tmp, int E) {
    __shared__ int cur[NB];
    for (int i = threadIdx.x; i < NB; i += 256) cur[i] = bhs[i * NBLK + blockIdx.x];
    __syncthreads();
    const int base = blockIdx.x * EPB;
    const int end = min(base + EPB, E);
    for (int i = base + threadIdx.x; i < end; i += 256) {
        int d = dst[i];
        int p = atomicAdd(&cur[d >> 7], 1);
        tmp[p] = (src[i] << 7) | (d & 127);
    }
}

// bucket: one block per bucket — 128-counter local sort; writes offs + csr
__global__ __launch_bounds__(256)
void bucket_k(const int* __restrict__ tmp, const int* __restrict__ bhs,
              int* __restrict__ offs, int* __restrict__ csr, int E, int N) {
    const int b = blockIdx.x;
    const int t = threadIdx.x;
    __shared__ int hist[128], excl[128], cur[128];
    const int bstart = bhs[b * NBLK];
    const int bend = (b + 1 < NB) ? bhs[(b + 1) * NBLK] : E;
    if (t < 128) hist[t] = 0;
    __syncthreads();
    for (int i = bstart + t; i < bend; i += 256)
        atomicAdd(&hist[tmp[i] & 127], 1);
    __syncthreads();
    if (t < 128) excl[t] = hist[t];
    __syncthreads();
    for (int o = 1; o < 128; o <<= 1) {
        int u = (t < 128 && t >= o) ? excl[t - o] : 0;
        __syncthreads();
        if (t < 128) excl[t] += u;
        __syncthreads();
    }
    const int node0 = b * 128;
    if (t < 128) {
        int base = bstart + ((t == 0) ? 0 : excl[t - 1]);
        if (node0 + t < N) offs[node0 + t] = base;
        cur[t] = base;
    }
    if (b == 0 && t == 0) offs[N] = E;
    __syncthreads();
    for (int i = bstart + t; i < bend; i += 256) {
        int e = tmp[i];
        int p = atomicAdd(&cur[e & 127], 1);
        csr[p] = e >> 7;
    }
}

// ------------------------------------------- standalone gather-aggregate
// Pure gather kernel: 16 nodes per 256-block, one quarter-wave
// (16 lanes x hv8 = full 256 B row) per node. Unroll-8: 8 rows in flight
// per quarter-wave (~64 VGPR: 8 addr + 32 load + 16 accum).
__global__ __launch_bounds__(256)
void agg16_k(const _Float16* __restrict__ h_in,
             const int* __restrict__ offs, const int* __restrict__ csr,
             const float* __restrict__ eps, int layer,
             _Float16* __restrict__ z) {
    const int qw = threadIdx.x >> 4;           // 0..15
    const int l16 = threadIdx.x & 15;
    const int node = blockIdx.x * 16 + qw;
    if (node >= N_NODES) return;
    const hv8* __restrict__ h8 = (const hv8*)h_in;   // row = 16 hv8
    const float sc = 1.0f + eps[layer];
    const int beg = offs[node], end = offs[node + 1];
    float a0[8] = {0,0,0,0,0,0,0,0};
    float a1[8] = {0,0,0,0,0,0,0,0};
    int j = beg;
    for (; j + 8 <= end; j += 8) {
        int s0 = csr[j],   s1 = csr[j+1], s2 = csr[j+2], s3 = csr[j+3];
        int s4 = csr[j+4], s5 = csr[j+5], s6 = csr[j+6], s7 = csr[j+7];
        hv8 v0 = h8[(size_t)s0 * 16 + l16];
        hv8 v1 = h8[(size_t)s1 * 16 + l16];
        hv8 v2 = h8[(size_t)s2 * 16 + l16];
        hv8 v3 = h8[(size_t)s3 * 16 + l16];
        hv8 v4 = h8[(size_t)s4 * 16 + l16];
        hv8 v5 = h8[(size_t)s5 * 16 + l16];
        hv8 v6 = h8[(size_t)s6 * 16 + l16];
        hv8 v7 = h8[(size_t)s7 * 16 + l16];
#pragma unroll
        for (int e = 0; e < 8; ++e) {
            a0[e] += ((float)v0[e] + (float)v2[e]) + ((float)v4[e] + (float)v6[e]);
            a1[e] += ((float)v1[e] + (float)v3[e]) + ((float)v5[e] + (float)v7[e]);
        }
    }
    for (; j + 2 <= end; j += 2) {
        int s0 = csr[j], s1 = csr[j+1];
        hv8 v0 = h8[(size_t)s0 * 16 + l16];
        hv8 v1 = h8[(size_t)s1 * 16 + l16];
#pragma unroll
        for (int e = 0; e < 8; ++e) {
            a0[e] += (float)v0[e];
            a1[e] += (float)v1[e];
        }
    }
    if (j < end) {
        hv8 v = h8[(size_t)csr[j] * 16 + l16];
#pragma unroll
        for (int e = 0; e < 8; ++e) a0[e] += (float)v[e];
    }
    hv8 self = h8[(size_t)node * 16 + l16];
    hv8 o;
#pragma unroll
    for (int e = 0; e < 8; ++e)
        o[e] = (_Float16)(sc * (float)self[e] + (a0[e] + a1[e]));
    ((hv8*)z)[(size_t)node * 16 + l16] = o;
}

// ------------------------------------------------------- MLP kernel (v4)
// One block = 64 rows (grid 782). Fragment-major W, streamed per k-step.
// !HEAD h-store goes through LDS restage -> coalesced hv8 global stores.
// FP accumulate order per acc element unchanged (ks ascending).
template <bool HEAD>
__global__ __launch_bounds__(256)
void mlp_k(const _Float16* __restrict__ z_in,
           const unsigned short* __restrict__ WAhi, const unsigned short* __restrict__ WAlo,
           const float* __restrict__ ba,
           const unsigned short* __restrict__ WBhi, const unsigned short* __restrict__ WBlo,
           const float* __restrict__ bb,
           const unsigned short* __restrict__ WHhi, const unsigned short* __restrict__ WHlo,
           const float* __restrict__ bh1,
           const float* __restrict__ W2, const float* __restrict__ b2,
           void* __restrict__ outp) {
    __shared__ unsigned short Zhi[64 * 136];   // 17,408 B
    __shared__ unsigned short Zlo[64 * 136];
    const int t = threadIdx.x;
    const int wave = t >> 6, lane = t & 63;
    const int m = lane & 15, quad = lane >> 4;
    const int row0 = blockIdx.x * 64;

    // ---------- stage z -> LDS bf16 hi/lo (coalesced hv8 reads)
    {
        const int quart = lane >> 4, l16 = lane & 15;
        const hv8* __restrict__ z8 = (const hv8*)z_in;
        for (int g = 0; g < 4; ++g) {
            const int r = wave * 16 + g * 4 + quart;
            const int node = row0 + r;
            float o[8] = {0,0,0,0,0,0,0,0};
            if (node < N_NODES) {
                hv8 v = z8[(size_t)node * 16 + l16];
#pragma unroll
                for (int e = 0; e < 8; ++e) o[e] = (float)v[e];
            }
            us4 hi0, hi1, lo0, lo1;
#pragma unroll
            for (int e = 0; e < 4; ++e) {
                hi0[e] = f2bf(o[e]);     lo0[e] = f2bf(o[e]     - bf2f(hi0[e]));
                hi1[e] = f2bf(o[e + 4]); lo1[e] = f2bf(o[e + 4] - bf2f(hi1[e]));
            }
            *(us4*)&Zhi[r * 136 + l16 * 8]     = hi0;
            *(us4*)&Zhi[r * 136 + l16 * 8 + 4] = hi1;
            *(us4*)&Zlo[r * 136 + l16 * 8]     = lo0;
            *(us4*)&Zlo[r * 136 + l16 * 8 + 4] = lo1;
        }
    }
    __syncthreads();

    // ---------- phase 2: z @ W_a (fragment-major W, streamed per ks)
    f32x4 acc[4][2];
    for (int s = 0; s < 4; ++s)
        for (int ct = 0; ct < 2; ++ct) acc[s][ct] = (f32x4){0, 0, 0, 0};
#pragma unroll 1
    for (int ks = 0; ks < 4; ++ks) {
        const int fA = (wave * 8 + ks * 2) * 512 + lane * 8;
        short8 wh0 = *(const short8*)&WAhi[fA];
        short8 wl0 = *(const short8*)&WAlo[fA];
        short8 wh1 = *(const short8*)&WAhi[fA + 512];
        short8 wl1 = *(const short8*)&WAlo[fA + 512];
        const int wo = ks * 32 + quad * 8;
#pragma unroll
        for (int s = 0; s < 4; ++s) {
            const int r = s * 16 + m;
            short8 zh = *(const short8*)&Zhi[r * 136 + wo];
            short8 zl = *(const short8*)&Zlo[r * 136 + wo];
            acc[s][0] = __builtin_amdgcn_mfma_f32_16x16x32_bf16(zh, wh0, acc[s][0], 0, 0, 0);
            acc[s][0] = __builtin_amdgcn_mfma_f32_16x16x32_bf16(zh, wl0, acc[s][0], 0, 0, 0);
            acc[s][0] = __builtin_amdgcn_mfma_f32_16x16x32_bf16(zl, wh0, acc[s][0], 0, 0, 0);
            acc[s][1] = __builtin_amdgcn_mfma_f32_16x16x32_bf16(zh, wh1, acc[s][1], 0, 0, 0);
            acc[s][1] = __builtin_amdgcn_mfma_f32_16x16x32_bf16(zh, wl1, acc[s][1], 0, 0, 0);
            acc[s][1] = __builtin_amdgcn_mfma_f32_16x16x32_bf16(zl, wh1, acc[s][1], 0, 0, 0);
        }
    }
    __syncthreads();   // all z reads done; safe to overwrite LDS

    // ---------- u = relu(acc + ba) -> LDS bf16 hi/lo
    for (int s = 0; s < 4; ++s) {
        for (int ct = 0; ct < 2; ++ct) {
            int c = wave * 32 + ct * 16 + m;
            float bac = ba[c];
            for (int i = 0; i < 4; ++i) {
                int r = s * 16 + quad * 4 + i;
                float v = fmaxf(acc[s][ct][i] + bac, 0.0f);
                unsigned short hv = f2bf(v);
                Zhi[r * 136 + c] = hv;
                Zlo[r * 136 + c] = f2bf(v - bf2f(hv));
            }
        }
    }
    __syncthreads();

    // ---------- phase 3: u @ W_b
    for (int s = 0; s < 4; ++s)
        for (int ct = 0; ct < 2; ++ct) acc[s][ct] = (f32x4){0, 0, 0, 0};
#pragma unroll 1
    for (int ks = 0; ks < 4; ++ks) {
        const int fB = (wave * 8 + ks * 2) * 512 + lane * 8;
        short8 wh0 = *(const short8*)&WBhi[fB];
        short8 wl0 = *(const short8*)&WBlo[fB];
        short8 wh1 = *(const short8*)&WBhi[fB + 512];
        short8 wl1 = *(const short8*)&WBlo[fB + 512];
        const int wo = ks * 32 + quad * 8;
#pragma unroll
        for (int s = 0; s < 4; ++s) {
            const int r = s * 16 + m;
            short8 zh = *(const short8*)&Zhi[r * 136 + wo];
            short8 zl = *(const short8*)&Zlo[r * 136 + wo];
            acc[s][0] = __builtin_amdgcn_mfma_f32_16x16x32_bf16(zh, wh0, acc[s][0], 0, 0, 0);
            acc[s][0] = __builtin_amdgcn_mfma_f32_16x16x32_bf16(zh, wl0, acc[s][0], 0, 0, 0);
            acc[s][0] = __builtin_amdgcn_mfma_f32_16x16x32_bf16(zl, wh0, acc[s][0], 0, 0, 0);
            acc[s][1] = __builtin_amdgcn_mfma_f32_16x16x32_bf16(zh, wh1, acc[s][1], 0, 0, 0);
            acc[s][1] = __builtin_amdgcn_mfma_f32_16x16x32_bf16(zh, wl1, acc[s][1], 0, 0, 0);
            acc[s][1] = __builtin_amdgcn_mfma_f32_16x16x32_bf16(zl, wh1, acc[s][1], 0, 0, 0);
        }
    }

    if (!HEAD) {
        // ---------- h = relu(acc + bb) -> LDS (fp16) -> coalesced global
        __syncthreads();   // phase-3 LDS reads done; reuse Zhi as fp16
        _Float16* Uh = (_Float16*)Zhi;   // 64 x 136 fp16
        for (int s = 0; s < 4; ++s) {
            for (int ct = 0; ct < 2; ++ct) {
                int c = wave * 32 + ct * 16 + m;
                float bbc = bb[c];
                for (int i = 0; i < 4; ++i) {
                    int r = s * 16 + quad * 4 + i;
                    Uh[r * 136 + c] = (_Float16)fmaxf(acc[s][ct][i] + bbc, 0.0f);
                }
            }
        }
        __syncthreads();
        _Float16* hout = (_Float16*)outp;
        const int quart = lane >> 4, l16 = lane & 15;
        for (int g = 0; g < 4; ++g) {
            int r = wave * 16 + g * 4 + quart;
            int node = row0 + r;
            if (node < N_NODES) {
                hv8 v = *(hv8*)&Uh[r * 136 + l16 * 8];
                ((hv8*)hout)[(size_t)node * 16 + l16] = v;
            }
        }
    } else {
        __syncthreads();   // all u reads done; safe to overwrite LDS

        // ---------- h = relu(acc + bb) -> LDS bf16 hi/lo
        for (int s = 0; s < 4; ++s) {
            for (int ct = 0; ct < 2; ++ct) {
                int c = wave * 32 + ct * 16 + m;
                float bbc = bb[c];
                for (int i = 0; i < 4; ++i) {
                    int r = s * 16 + quad * 4 + i;
                    float v = fmaxf(acc[s][ct][i] + bbc, 0.0f);
                    unsigned short hv = f2bf(v);
                    Zhi[r * 136 + c] = hv;
                    Zlo[r * 136 + c] = f2bf(v - bf2f(hv));
                }
            }
        }
        __syncthreads();

        // ---------- phase 4: h @ W_h1 (128 -> 64), fragment-major, streamed
        f32x4 a3[4];
        for (int s = 0; s < 4; ++s) a3[s] = (f32x4){0, 0, 0, 0};
#pragma unroll 1
        for (int ks = 0; ks < 4; ++ks) {
            const int fH = (wave * 4 + ks) * 512 + lane * 8;
            short8 hh = *(const short8*)&WHhi[fH];
            short8 hl = *(const short8*)&WHlo[fH];
            const int wo = ks * 32 + quad * 8;
#pragma unroll
            for (int s = 0; s < 4; ++s) {
                const int r = s * 16 + m;
                short8 zh = *(const short8*)&Zhi[r * 136 + wo];
                short8 zl = *(const short8*)&Zlo[r * 136 + wo];
                a3[s] = __builtin_amdgcn_mfma_f32_16x16x32_bf16(zh, hh, a3[s], 0, 0, 0);
                a3[s] = __builtin_amdgcn_mfma_f32_16x16x32_bf16(zh, hl, a3[s], 0, 0, 0);
                a3[s] = __builtin_amdgcn_mfma_f32_16x16x32_bf16(zl, hh, a3[s], 0, 0, 0);
            }
        }
        __syncthreads();   // phase-4 reads done; reuse LDS as fp32

        float* Hid = (float*)Zhi;   // 64 x 68 fp32 = 17,408 B (fits in Zhi)
        for (int s = 0; s < 4; ++s) {
            int c = wave * 16 + m;
            float bc = bh1[c];
            for (int i = 0; i < 4; ++i) {
                int r = s * 16 + quad * 4 + i;
                Hid[r * 68 + c] = fmaxf(a3[s][i] + bc, 0.0f);
            }
        }
        __syncthreads();

        // ---------- phase 5: hid @ W_h2 (64 -> 2) + b2 -> out
        float* Red = (float*)Zlo;   // 256 floats (Zlo free after phase 4)
        {
            int pair = t >> 1, seg = t & 1;
            int r = pair >> 1, col = pair & 1;
            float p = 0.0f;
#pragma unroll
            for (int j = seg * 32; j < seg * 32 + 32; ++j)
                p += Hid[r * 68 + j] * W2[j * 2 + col];
            Red[t] = p;
        }
        __syncthreads();
        if (t < 128) {
            float* outF = (float*)outp;
            int r = t >> 1, col = t & 1;
            float a = b2[col] + (Red[t * 2] + Red[t * 2 + 1]);
            int node = row0 + r;
            if (node < N_NODES) outF[(size_t)node * 2 + col] = a;
        }
    }
}

// ------------------------------------------------------------------ launch

extern "C" void kernel_launch(void* const* d_in, const int* in_sizes, int n_in,
                              void* d_out, int out_size, void* d_ws, size_t ws_size,
                              hipStream_t stream) {
    const float* x    = (const float*)d_in[0];
    const int*   ei   = (const int*)d_in[1];
    const float* eps  = (const float*)d_in[2];
    const float* W_a  = (const float*)d_in[3];
    const float* b_a  = (const float*)d_in[4];
    const float* W_b  = (const float*)d_in[5];
    const float* b_b  = (const float*)d_in[6];
    const float* W_h1 = (const float*)d_in[7];
    const float* b_h1 = (const float*)d_in[8];
    const float* W_h2 = (const float*)d_in[9];
    const float* b_h2 = (const float*)d_in[10];
    float* out = (float*)d_out;

    const int N = N_NODES, E = N_EDGES;
    const int* src = ei;
    const int* dst = ei + E;

    char* ws = (char*)d_ws;
    size_t off = 0;
    auto carve = [&](size_t bytes) {
        char* p = ws + off;
        off = (off + bytes + 255) & ~(size_t)255;
        return p;
    };
    _Float16* xh   = (_Float16*)carve((size_t)N * HID * sizeof(_Float16));
    _Float16* zb   = (_Float16*)carve((size_t)N * HID * sizeof(_Float16));
    _Float16* bufA = (_Float16*)carve((size_t)N * HID * sizeof(_Float16));
    _Float16* bufB = (_Float16*)carve((size_t)N * HID * sizeof(_Float16));
    int*   tmp    = (int*)carve((size_t)E * sizeof(int));
    int*   csr    = (int*)carve((size_t)E * sizeof(int));
    int*   offs   = (int*)carve((size_t)(N + 1) * sizeof(int));
    int*   bh     = (int*)carve((size_t)NB * NBLK * sizeof(int));
    int*   bhs    = (int*)carve((size_t)NB * NBLK * sizeof(int));
    int*   bsum   = (int*)carve(64 * sizeof(int));
    unsigned short* whi = (unsigned short*)carve(7 * 16384 * sizeof(unsigned short));
    unsigned short* wlo = (unsigned short*)carve(7 * 16384 * sizeof(unsigned short));
    (void)ws_size;

    // ---- merged histogram + converts, then scan/scatter/bucket
    const int M = NB * NBLK;                     // 62,560
    const int SB = (M + 2047) / 2048;            // 31 scan blocks
    histcvt_k<<<NBLK + CVTXB + CVTWB, 256, 0, stream>>>(
        dst, bh, E, x, xh, W_a, W_b, W_h1, whi, wlo);
    scanA_k<<<SB, 256, 0, stream>>>(bh, bsum, M);
    scanC_k<<<SB, 256, 0, stream>>>(bh, bsum, bhs, M, SB);
    scatter_k<<<NBLK, 256, 0, stream>>>(src, dst, bhs, tmp, E);
    bucket_k<<<NB, 256, 0, stream>>>(tmp, bhs, offs, csr, E, N);

    const int agg_grid = (N + 15) / 16;
    const int mlp_grid = (N + 63) / 64;
    #define WSLOT(s) (whi + (s) * 16384), (wlo + (s) * 16384)
    #define NOHEAD (const unsigned short*)nullptr, (const unsigned short*)nullptr, \
                   (const float*)nullptr, (const float*)nullptr, (const float*)nullptr

    // layer 0
    agg16_k<<<agg_grid, 256, 0, stream>>>(xh, offs, csr, eps, 0, zb);
    mlp_k<false><<<mlp_grid, 256, 0, stream>>>(zb, WSLOT(0), b_a + 0 * 128,
        WSLOT(1), b_b + 0 * 128, NOHEAD, (void*)bufA);
    // layer 1
    agg16_k<<<agg_grid, 256, 0, stream>>>(bufA, offs, csr, eps, 1, zb);
    mlp_k<false><<<mlp_grid, 256, 0, stream>>>(zb, WSLOT(2), b_a + 1 * 128,
        WSLOT(3), b_b + 1 * 128, NOHEAD, (void*)bufB);
    // layer 2 + head
    agg16_k<<<agg_grid, 256, 0, stream>>>(bufB, offs, csr, eps, 2, zb);
    mlp_k<true><<<mlp_grid, 256, 0, stream>>>(zb, WSLOT(4), b_a + 2 * 128,
        WSLOT(5), b_b + 2 * 128, WSLOT(6), b_h1, W_h2, b_h2, (void*)out);
}